// Round 2
// baseline (192.473 us; speedup 1.0000x reference)
//
#include <hip/hip_runtime.h>

#define DIMS 128
#define NCLS 16
#define NPROJ 32  // src 16 + dst 16

// ---------------- Phase 1: per-node projection P[n][32] ----------------
// P[n][c]      = sum_d h[n][d] * W[c][d] + b[c]   (c in 0..15, src half; b folded here)
// P[n][16+c]   = sum_d h[n][d] * W[c][128+d]      (dst half)
//
// W is read with wave-uniform addresses (loop constants only) so the
// compiler emits s_load (scalar pipe, K$-cached: W = 16 KB). This keeps the
// LDS pipe idle; the inner loop is pure VALU fed by SMEM. h is streamed as
// float4 (coalesced, 512 B per wave per load).
__global__ __launch_bounds__(256) void proj_kernel(
    const float* __restrict__ h, const float* __restrict__ W,
    const float* __restrict__ b, float* __restrict__ P, int n_nodes) {
  int node = blockIdx.x * blockDim.x + threadIdx.x;
  if (node >= n_nodes) return;

  const float4* h4 = reinterpret_cast<const float4*>(h + (size_t)node * DIMS);

  float acc[NPROJ];
#pragma unroll
  for (int c = 0; c < NPROJ; ++c) acc[c] = 0.f;

#pragma unroll 4
  for (int dc = 0; dc < DIMS / 4; ++dc) {
    float4 hv = h4[dc];
#pragma unroll
    for (int c = 0; c < NPROJ; ++c) {
      // class (c&15), half (c>>4): uniform address -> s_load_dwordx4
      const float4 wv = *reinterpret_cast<const float4*>(
          W + (size_t)((c & 15) * 2 * DIMS + ((c >> 4) << 7) + (dc << 2)));
      float a = acc[c];
      a = fmaf(hv.x, wv.x, a);
      a = fmaf(hv.y, wv.y, a);
      a = fmaf(hv.z, wv.z, a);
      a = fmaf(hv.w, wv.w, a);
      acc[c] = a;
    }
  }

  // Fold bias into the src half so gather never reads b.
#pragma unroll
  for (int c = 0; c < NCLS; ++c) acc[c] += b[c];

  float4* Po = reinterpret_cast<float4*>(P + (size_t)node * NPROJ);
#pragma unroll
  for (int q = 0; q < NPROJ / 4; ++q) {
    Po[q] = make_float4(acc[q * 4 + 0], acc[q * 4 + 1],
                        acc[q * 4 + 2], acc[q * 4 + 3]);
  }
}

// ---------------- Phase 2: per-edge gather + add ----------------
// thread t -> edge e = t/16, class c = t%16
// out[e][c] = P[src[e]][c] + P[dst[e]][16+c]     (b already folded into P)
// Output store is nontemporal: 38 MB of streaming writes must not evict the
// L3-resident P (12.8 MB) that the gathers depend on.
__global__ __launch_bounds__(256) void gather_kernel(
    const int* __restrict__ esrc, const int* __restrict__ edst,
    const float* __restrict__ P, float* __restrict__ out, int n_edges) {
  long t = (long)blockIdx.x * blockDim.x + threadIdx.x;
  int e = (int)(t >> 4);
  if (e >= n_edges) return;
  int c = (int)(t & 15);
  int s = esrc[e];
  int d = edst[e];
  float v = P[(size_t)s * NPROJ + c] + P[(size_t)d * NPROJ + NCLS + c];
  __builtin_nontemporal_store(v, &out[t]);
}

// ---------------- Fallback (only if workspace too small) ----------------
__global__ __launch_bounds__(256) void direct_kernel(
    const float* __restrict__ h, const int* __restrict__ esrc,
    const int* __restrict__ edst, const float* __restrict__ W,
    const float* __restrict__ b, float* __restrict__ out, int n_edges) {
  long t = (long)blockIdx.x * blockDim.x + threadIdx.x;
  int e = (int)(t >> 4);
  if (e >= n_edges) return;
  int c = (int)(t & 15);
  const float* hs = h + (size_t)esrc[e] * DIMS;
  const float* hd = h + (size_t)edst[e] * DIMS;
  float acc = b[c];
  for (int d0 = 0; d0 < DIMS; ++d0) {
    acc = fmaf(hs[d0], W[c * 2 * DIMS + d0], acc);
    acc = fmaf(hd[d0], W[c * 2 * DIMS + DIMS + d0], acc);
  }
  out[t] = acc;
}

extern "C" void kernel_launch(void* const* d_in, const int* in_sizes, int n_in,
                              void* d_out, int out_size, void* d_ws, size_t ws_size,
                              hipStream_t stream) {
  const float* h    = (const float*)d_in[0];
  const int*   esrc = (const int*)d_in[1];
  const int*   edst = (const int*)d_in[2];
  const float* W    = (const float*)d_in[3];
  const float* b    = (const float*)d_in[4];
  float* out = (float*)d_out;

  int n_nodes = in_sizes[0] / DIMS;
  int n_edges = in_sizes[1];

  size_t need = (size_t)n_nodes * NPROJ * sizeof(float);
  if (ws_size >= need) {
    float* P = (float*)d_ws;
    int blocks1 = (n_nodes + 255) / 256;
    proj_kernel<<<blocks1, 256, 0, stream>>>(h, W, b, P, n_nodes);
    long total = (long)n_edges * NCLS;
    int blocks2 = (int)((total + 255) / 256);
    gather_kernel<<<blocks2, 256, 0, stream>>>(esrc, edst, P, out, n_edges);
  } else {
    long total = (long)n_edges * NCLS;
    int blocks2 = (int)((total + 255) / 256);
    direct_kernel<<<blocks2, 256, 0, stream>>>(h, esrc, edst, W, b, out, n_edges);
  }
}

// Round 4
// 135.705 us; speedup vs baseline: 1.4183x; 1.4183x over previous
//
#include <hip/hip_runtime.h>
#include <hip/hip_bf16.h>

#define DIMS 128
#define NCLS 16
#define NPROJ 32  // src 16 + dst 16

typedef __attribute__((ext_vector_type(8))) short bf16x8;
typedef __attribute__((ext_vector_type(4))) float f32x4;

// float -> bf16 (RNE) bit trick; inputs are finite normals.
__device__ inline short f2bf(float f) {
  unsigned u = __builtin_bit_cast(unsigned, f);
  u += 0x7fffu + ((u >> 16) & 1u);
  return (short)(u >> 16);
}

__device__ inline bf16x8 pack8(float4 a, float4 b) {
  bf16x8 r;
  r[0] = f2bf(a.x); r[1] = f2bf(a.y); r[2] = f2bf(a.z); r[3] = f2bf(a.w);
  r[4] = f2bf(b.x); r[5] = f2bf(b.y); r[6] = f2bf(b.z); r[7] = f2bf(b.w);
  return r;
}

// ---------------- Phase 1: P = h . W^T via bf16 MFMA ----------------
// One wave computes 16 nodes x 32 projections. K=128 in 4 MFMA steps,
// 2 N-tiles (src classes 0-15, dst classes 16-31). No LDS, no barriers.
// A-frag: lane holds row = lane&15, k = (lane>>4)*8 + j   (+32*ks)
// B-frag: lane holds class = lane&15, same k mapping (W^T as K x N)
// D: col(class) = lane&15, row = (lane>>4)*4 + r  [verified layout]
__global__ __launch_bounds__(256) void proj_mfma_kernel(
    const float* __restrict__ h, const float* __restrict__ W,
    const float* __restrict__ b, float* __restrict__ P, int n_nodes) {
  const int lane = threadIdx.x & 63;
  const int wave = threadIdx.x >> 6;
  const int row_base = blockIdx.x * 64 + wave * 16;
  if (row_base >= n_nodes) return;

  const int m  = lane & 15;   // A-row / B-class index
  const int kg = lane >> 4;   // k-group 0..3

  int row = row_base + m;
  int row_c = row < n_nodes ? row : n_nodes - 1;  // clamp for tail loads

  // --- A fragments: h[row][kg*8 + ks*32 .. +7] ---
  const float* hrow = h + (size_t)row_c * DIMS;
  bf16x8 afrag[4];
#pragma unroll
  for (int ks = 0; ks < 4; ++ks) {
    float4 f0 = *reinterpret_cast<const float4*>(hrow + ks * 32 + kg * 8);
    float4 f1 = *reinterpret_cast<const float4*>(hrow + ks * 32 + kg * 8 + 4);
    afrag[ks] = pack8(f0, f1);
  }

  // --- B fragments: W[class][half*128 + ks*32 + kg*8 .. +7] (L2-hot, 16KB) ---
  const float* wrow = W + (size_t)m * (2 * DIMS);
  bf16x8 bfrag[2][4];
#pragma unroll
  for (int half = 0; half < 2; ++half) {
#pragma unroll
    for (int ks = 0; ks < 4; ++ks) {
      const float* wp = wrow + half * DIMS + ks * 32 + kg * 8;
      float4 f0 = *reinterpret_cast<const float4*>(wp);
      float4 f1 = *reinterpret_cast<const float4*>(wp + 4);
      bfrag[half][ks] = pack8(f0, f1);
    }
  }

  f32x4 acc0 = {0.f, 0.f, 0.f, 0.f};  // src classes
  f32x4 acc1 = {0.f, 0.f, 0.f, 0.f};  // dst classes
#pragma unroll
  for (int ks = 0; ks < 4; ++ks) {
    acc0 = __builtin_amdgcn_mfma_f32_16x16x32_bf16(afrag[ks], bfrag[0][ks], acc0, 0, 0, 0);
    acc1 = __builtin_amdgcn_mfma_f32_16x16x32_bf16(afrag[ks], bfrag[1][ks], acc1, 0, 0, 0);
  }

  // --- epilogue: fold bias into src half, store P[node][32] ---
  float bias = b[m];
#pragma unroll
  for (int r = 0; r < 4; ++r) {
    int orow = row_base + kg * 4 + r;
    if (orow < n_nodes) {
      P[(size_t)orow * NPROJ + m]        = acc0[r] + bias;
      P[(size_t)orow * NPROJ + NCLS + m] = acc1[r];
    }
  }
}

// ---------------- Phase 2: per-edge gather + add ----------------
// thread t -> edge e = t/16, class c = t%16
// out[e][c] = P[src[e]][c] + P[dst[e]][16+c]   (b folded into P src half)
__global__ __launch_bounds__(256) void gather_kernel(
    const int* __restrict__ esrc, const int* __restrict__ edst,
    const float* __restrict__ P, float* __restrict__ out, int n_edges) {
  long t = (long)blockIdx.x * blockDim.x + threadIdx.x;
  int e = (int)(t >> 4);
  if (e >= n_edges) return;
  int c = (int)(t & 15);
  int s = esrc[e];
  int d = edst[e];
  float v = P[(size_t)s * NPROJ + c] + P[(size_t)d * NPROJ + NCLS + c];
  __builtin_nontemporal_store(v, &out[t]);
}

// ---------------- Fallback (only if workspace too small) ----------------
__global__ __launch_bounds__(256) void direct_kernel(
    const float* __restrict__ h, const int* __restrict__ esrc,
    const int* __restrict__ edst, const float* __restrict__ W,
    const float* __restrict__ b, float* __restrict__ out, int n_edges) {
  long t = (long)blockIdx.x * blockDim.x + threadIdx.x;
  int e = (int)(t >> 4);
  if (e >= n_edges) return;
  int c = (int)(t & 15);
  const float* hs = h + (size_t)esrc[e] * DIMS;
  const float* hd = h + (size_t)edst[e] * DIMS;
  float acc = b[c];
  for (int d0 = 0; d0 < DIMS; ++d0) {
    acc = fmaf(hs[d0], W[c * 2 * DIMS + d0], acc);
    acc = fmaf(hd[d0], W[c * 2 * DIMS + DIMS + d0], acc);
  }
  out[t] = acc;
}

extern "C" void kernel_launch(void* const* d_in, const int* in_sizes, int n_in,
                              void* d_out, int out_size, void* d_ws, size_t ws_size,
                              hipStream_t stream) {
  const float* h    = (const float*)d_in[0];
  const int*   esrc = (const int*)d_in[1];
  const int*   edst = (const int*)d_in[2];
  const float* W    = (const float*)d_in[3];
  const float* b    = (const float*)d_in[4];
  float* out = (float*)d_out;

  int n_nodes = in_sizes[0] / DIMS;
  int n_edges = in_sizes[1];

  size_t need = (size_t)n_nodes * NPROJ * sizeof(float);
  if (ws_size >= need) {
    float* P = (float*)d_ws;
    int blocks1 = (n_nodes + 63) / 64;  // 64 nodes per 256-thread block (4 waves x 16)
    proj_mfma_kernel<<<blocks1, 256, 0, stream>>>(h, W, b, P, n_nodes);
    long total = (long)n_edges * NCLS;
    int blocks2 = (int)((total + 255) / 256);
    gather_kernel<<<blocks2, 256, 0, stream>>>(esrc, edst, P, out, n_edges);
  } else {
    long total = (long)n_edges * NCLS;
    int blocks2 = (int)((total + 255) / 256);
    direct_kernel<<<blocks2, 256, 0, stream>>>(h, esrc, edst, W, b, out, n_edges);
  }
}

// Round 7
// 130.837 us; speedup vs baseline: 1.4711x; 1.0372x over previous
//
#include <hip/hip_runtime.h>
#include <hip/hip_bf16.h>

#define DIMS 128
#define NCLS 16
#define NPROJ 32  // src 16 + dst 16

typedef __attribute__((ext_vector_type(8))) short bf16x8;
typedef __attribute__((ext_vector_type(4))) float f32x4;

// float -> bf16 (RNE) bit trick; inputs are finite normals.
__device__ inline short f2bf(float f) {
  unsigned u = __builtin_bit_cast(unsigned, f);
  u += 0x7fffu + ((u >> 16) & 1u);
  return (short)(u >> 16);
}

__device__ inline bf16x8 pack8(float4 a, float4 b) {
  bf16x8 r;
  r[0] = f2bf(a.x); r[1] = f2bf(a.y); r[2] = f2bf(a.z); r[3] = f2bf(a.w);
  r[4] = f2bf(b.x); r[5] = f2bf(b.y); r[6] = f2bf(b.z); r[7] = f2bf(b.w);
  return r;
}

// ---------------- Phase 1: P = h . W^T via bf16 MFMA ----------------
// One wave computes 16 nodes x 32 projections. K=128 in 4 MFMA steps,
// 2 N-tiles (src classes 0-15, dst classes 16-31). No LDS, no barriers.
// A-frag: lane holds row = lane&15, k = (lane>>4)*8 + j   (+32*ks)
// B-frag: lane holds class = lane&15, same k mapping (W^T as K x N)
// D: col(class) = lane&15, row = (lane>>4)*4 + r  [verified layout]
__global__ __launch_bounds__(256) void proj_mfma_kernel(
    const float* __restrict__ h, const float* __restrict__ W,
    const float* __restrict__ b, float* __restrict__ P, int n_nodes) {
  const int lane = threadIdx.x & 63;
  const int wave = threadIdx.x >> 6;
  const int row_base = blockIdx.x * 64 + wave * 16;
  if (row_base >= n_nodes) return;

  const int m  = lane & 15;   // A-row / B-class index
  const int kg = lane >> 4;   // k-group 0..3

  int row = row_base + m;
  int row_c = row < n_nodes ? row : n_nodes - 1;  // clamp for tail loads

  // --- A fragments: h[row][kg*8 + ks*32 .. +7] ---
  const float* hrow = h + (size_t)row_c * DIMS;
  bf16x8 afrag[4];
#pragma unroll
  for (int ks = 0; ks < 4; ++ks) {
    float4 f0 = *reinterpret_cast<const float4*>(hrow + ks * 32 + kg * 8);
    float4 f1 = *reinterpret_cast<const float4*>(hrow + ks * 32 + kg * 8 + 4);
    afrag[ks] = pack8(f0, f1);
  }

  // --- B fragments: W[class][half*128 + ks*32 + kg*8 .. +7] (L2-hot, 16KB) ---
  const float* wrow = W + (size_t)m * (2 * DIMS);
  bf16x8 bfrag[2][4];
#pragma unroll
  for (int half = 0; half < 2; ++half) {
#pragma unroll
    for (int ks = 0; ks < 4; ++ks) {
      const float* wp = wrow + half * DIMS + ks * 32 + kg * 8;
      float4 f0 = *reinterpret_cast<const float4*>(wp);
      float4 f1 = *reinterpret_cast<const float4*>(wp + 4);
      bfrag[half][ks] = pack8(f0, f1);
    }
  }

  f32x4 acc0 = {0.f, 0.f, 0.f, 0.f};  // src classes
  f32x4 acc1 = {0.f, 0.f, 0.f, 0.f};  // dst classes
#pragma unroll
  for (int ks = 0; ks < 4; ++ks) {
    acc0 = __builtin_amdgcn_mfma_f32_16x16x32_bf16(afrag[ks], bfrag[0][ks], acc0, 0, 0, 0);
    acc1 = __builtin_amdgcn_mfma_f32_16x16x32_bf16(afrag[ks], bfrag[1][ks], acc1, 0, 0, 0);
  }

  // --- epilogue: fold bias into src half, store P[node][32] ---
  float bias = b[m];
#pragma unroll
  for (int r = 0; r < 4; ++r) {
    int orow = row_base + kg * 4 + r;
    if (orow < n_nodes) {
      P[(size_t)orow * NPROJ + m]        = acc0[r] + bias;
      P[(size_t)orow * NPROJ + NCLS + m] = acc1[r];
    }
  }
}

// ---------------- Phase 2: per-edge gather + add (float4) ----------------
// 4 threads per edge; thread handles classes q*4..q*4+3.
// out[e][c] = P[src[e]][c] + P[dst[e]][16+c]   (b folded into P src half)
// vs 1-thread-per-class: 4x fewer redundant index loads, ~5x fewer VMEM
// instructions, identical bytes. Output store coalesced 16B/lane.
// NOTE: nontemporal store must use an ext_vector type (f32x4), not HIP's
// float4 class — the builtin rejects HIP_vector_type pointers.
__global__ __launch_bounds__(256) void gather4_kernel(
    const int* __restrict__ esrc, const int* __restrict__ edst,
    const float* __restrict__ P, float* __restrict__ out, int n_edges) {
  long t = (long)blockIdx.x * blockDim.x + threadIdx.x;
  int e = (int)(t >> 2);
  if (e >= n_edges) return;
  int q = (int)(t & 3);
  int s = esrc[e];
  int d = edst[e];
  f32x4 vs = *reinterpret_cast<const f32x4*>(P + (size_t)s * NPROJ + q * 4);
  f32x4 vd = *reinterpret_cast<const f32x4*>(P + (size_t)d * NPROJ + NCLS + q * 4);
  f32x4 v = vs + vd;
  __builtin_nontemporal_store(v, reinterpret_cast<f32x4*>(out + (size_t)t * 4));
}

// ---------------- Fallback (only if workspace too small) ----------------
__global__ __launch_bounds__(256) void direct_kernel(
    const float* __restrict__ h, const int* __restrict__ esrc,
    const int* __restrict__ edst, const float* __restrict__ W,
    const float* __restrict__ b, float* __restrict__ out, int n_edges) {
  long t = (long)blockIdx.x * blockDim.x + threadIdx.x;
  int e = (int)(t >> 4);
  if (e >= n_edges) return;
  int c = (int)(t & 15);
  const float* hs = h + (size_t)esrc[e] * DIMS;
  const float* hd = h + (size_t)edst[e] * DIMS;
  float acc = b[c];
  for (int d0 = 0; d0 < DIMS; ++d0) {
    acc = fmaf(hs[d0], W[c * 2 * DIMS + d0], acc);
    acc = fmaf(hd[d0], W[c * 2 * DIMS + DIMS + d0], acc);
  }
  out[t] = acc;
}

extern "C" void kernel_launch(void* const* d_in, const int* in_sizes, int n_in,
                              void* d_out, int out_size, void* d_ws, size_t ws_size,
                              hipStream_t stream) {
  const float* h    = (const float*)d_in[0];
  const int*   esrc = (const int*)d_in[1];
  const int*   edst = (const int*)d_in[2];
  const float* W    = (const float*)d_in[3];
  const float* b    = (const float*)d_in[4];
  float* out = (float*)d_out;

  int n_nodes = in_sizes[0] / DIMS;
  int n_edges = in_sizes[1];

  size_t need = (size_t)n_nodes * NPROJ * sizeof(float);
  if (ws_size >= need) {
    float* P = (float*)d_ws;
    int blocks1 = (n_nodes + 63) / 64;  // 64 nodes per 256-thread block (4 waves x 16)
    proj_mfma_kernel<<<blocks1, 256, 0, stream>>>(h, W, b, P, n_nodes);
    long total = (long)n_edges * 4;     // 4 threads per edge
    int blocks2 = (int)((total + 255) / 256);
    gather4_kernel<<<blocks2, 256, 0, stream>>>(esrc, edst, P, out, n_edges);
  } else {
    long total = (long)n_edges * NCLS;
    int blocks2 = (int)((total + 255) / 256);
    direct_kernel<<<blocks2, 256, 0, stream>>>(h, esrc, edst, W, b, out, n_edges);
  }
}

// Round 8
// 128.632 us; speedup vs baseline: 1.4963x; 1.0171x over previous
//
#include <hip/hip_runtime.h>
#include <hip/hip_bf16.h>

#define DIMS 128
#define NCLS 16
#define NPROJ 32  // src 16 + dst 16

typedef __attribute__((ext_vector_type(8))) short bf16x8;
typedef __attribute__((ext_vector_type(4))) float f32x4;

// float -> bf16 (RNE) bit trick; inputs are finite normals.
__device__ inline short f2bf(float f) {
  unsigned u = __builtin_bit_cast(unsigned, f);
  u += 0x7fffu + ((u >> 16) & 1u);
  return (short)(u >> 16);
}

__device__ inline float bf2f(unsigned short u) {
  unsigned x = ((unsigned)u) << 16;
  return __builtin_bit_cast(float, x);
}

__device__ inline bf16x8 pack8(float4 a, float4 b) {
  bf16x8 r;
  r[0] = f2bf(a.x); r[1] = f2bf(a.y); r[2] = f2bf(a.z); r[3] = f2bf(a.w);
  r[4] = f2bf(b.x); r[5] = f2bf(b.y); r[6] = f2bf(b.z); r[7] = f2bf(b.w);
  return r;
}

// ---------------- Phase 1: P = h . W^T via bf16 MFMA ----------------
// One wave computes 16 nodes x 32 projections. K=128 in 4 MFMA steps,
// 2 N-tiles (src classes 0-15, dst classes 16-31). No LDS, no barriers.
// P stored as TWO bf16 planes (Psrc[node][16], Pdst[node][16], 32 B rows):
// halves proj write traffic AND halves gather's random-read working set
// (6.4 MB -> much better per-XCD L2 residency).
// A-frag: lane holds row = lane&15, k = (lane>>4)*8 + j   (+32*ks)
// B-frag: lane holds class = lane&15, same k mapping (W^T as K x N)
// D: col(class) = lane&15, row = (lane>>4)*4 + r  [verified layout]
__global__ __launch_bounds__(256) void proj_mfma_kernel(
    const float* __restrict__ h, const float* __restrict__ W,
    const float* __restrict__ b, unsigned short* __restrict__ Psrc,
    unsigned short* __restrict__ Pdst, int n_nodes) {
  const int lane = threadIdx.x & 63;
  const int wave = threadIdx.x >> 6;
  const int row_base = blockIdx.x * 64 + wave * 16;
  if (row_base >= n_nodes) return;

  const int m  = lane & 15;   // A-row / B-class index
  const int kg = lane >> 4;   // k-group 0..3

  int row = row_base + m;
  int row_c = row < n_nodes ? row : n_nodes - 1;  // clamp for tail loads

  // --- A fragments: h[row][kg*8 + ks*32 .. +7] ---
  const float* hrow = h + (size_t)row_c * DIMS;
  bf16x8 afrag[4];
#pragma unroll
  for (int ks = 0; ks < 4; ++ks) {
    float4 f0 = *reinterpret_cast<const float4*>(hrow + ks * 32 + kg * 8);
    float4 f1 = *reinterpret_cast<const float4*>(hrow + ks * 32 + kg * 8 + 4);
    afrag[ks] = pack8(f0, f1);
  }

  // --- B fragments: W[class][half*128 + ks*32 + kg*8 .. +7] (L2-hot, 16KB) ---
  const float* wrow = W + (size_t)m * (2 * DIMS);
  bf16x8 bfrag[2][4];
#pragma unroll
  for (int half = 0; half < 2; ++half) {
#pragma unroll
    for (int ks = 0; ks < 4; ++ks) {
      const float* wp = wrow + half * DIMS + ks * 32 + kg * 8;
      float4 f0 = *reinterpret_cast<const float4*>(wp);
      float4 f1 = *reinterpret_cast<const float4*>(wp + 4);
      bfrag[half][ks] = pack8(f0, f1);
    }
  }

  f32x4 acc0 = {0.f, 0.f, 0.f, 0.f};  // src classes
  f32x4 acc1 = {0.f, 0.f, 0.f, 0.f};  // dst classes
#pragma unroll
  for (int ks = 0; ks < 4; ++ks) {
    acc0 = __builtin_amdgcn_mfma_f32_16x16x32_bf16(afrag[ks], bfrag[0][ks], acc0, 0, 0, 0);
    acc1 = __builtin_amdgcn_mfma_f32_16x16x32_bf16(afrag[ks], bfrag[1][ks], acc1, 0, 0, 0);
  }

  // --- epilogue: fold bias into src half, store bf16 planes ---
  // 2 B stores; each kg-group's 16 lanes cover 32 B contiguous -> 4 segments
  // per store inst. 6.4 MB total, write-combined in L2.
  float bias = b[m];
#pragma unroll
  for (int r = 0; r < 4; ++r) {
    int orow = row_base + kg * 4 + r;
    if (orow < n_nodes) {
      Psrc[(size_t)orow * NCLS + m] = (unsigned short)f2bf(acc0[r] + bias);
      Pdst[(size_t)orow * NCLS + m] = (unsigned short)f2bf(acc1[r]);
    }
  }
}

// ---------------- Phase 2: per-edge gather + add (bf16 planes) ----------------
// 2 threads per edge; thread q handles classes q*8..q*8+7.
// out[e][c] = Psrc[src[e]][c] + Pdst[dst[e]][c]   (b folded into Psrc)
// Per edge: 4 idx loads + 2x16B gathers + 2x32B coalesced NT stores.
__global__ __launch_bounds__(256) void gather2_kernel(
    const int* __restrict__ esrc, const int* __restrict__ edst,
    const unsigned short* __restrict__ Psrc, const unsigned short* __restrict__ Pdst,
    float* __restrict__ out, int n_edges) {
  long t = (long)blockIdx.x * blockDim.x + threadIdx.x;
  int e = (int)(t >> 1);
  if (e >= n_edges) return;
  int q = (int)(t & 1);
  int s = esrc[e];
  int d = edst[e];
  bf16x8 vs = *reinterpret_cast<const bf16x8*>(Psrc + (size_t)s * NCLS + q * 8);
  bf16x8 vd = *reinterpret_cast<const bf16x8*>(Pdst + (size_t)d * NCLS + q * 8);
  f32x4 lo, hi;
#pragma unroll
  for (int j = 0; j < 4; ++j) {
    lo[j] = bf2f((unsigned short)vs[j]) + bf2f((unsigned short)vd[j]);
    hi[j] = bf2f((unsigned short)vs[j + 4]) + bf2f((unsigned short)vd[j + 4]);
  }
  float* op = out + (size_t)t * 8;   // 32 B/lane, consecutive lanes contiguous
  __builtin_nontemporal_store(lo, reinterpret_cast<f32x4*>(op));
  __builtin_nontemporal_store(hi, reinterpret_cast<f32x4*>(op + 4));
}

// ---------------- Fallback (only if workspace too small) ----------------
__global__ __launch_bounds__(256) void direct_kernel(
    const float* __restrict__ h, const int* __restrict__ esrc,
    const int* __restrict__ edst, const float* __restrict__ W,
    const float* __restrict__ b, float* __restrict__ out, int n_edges) {
  long t = (long)blockIdx.x * blockDim.x + threadIdx.x;
  int e = (int)(t >> 4);
  if (e >= n_edges) return;
  int c = (int)(t & 15);
  const float* hs = h + (size_t)esrc[e] * DIMS;
  const float* hd = h + (size_t)edst[e] * DIMS;
  float acc = b[c];
  for (int d0 = 0; d0 < DIMS; ++d0) {
    acc = fmaf(hs[d0], W[c * 2 * DIMS + d0], acc);
    acc = fmaf(hd[d0], W[c * 2 * DIMS + DIMS + d0], acc);
  }
  out[t] = acc;
}

extern "C" void kernel_launch(void* const* d_in, const int* in_sizes, int n_in,
                              void* d_out, int out_size, void* d_ws, size_t ws_size,
                              hipStream_t stream) {
  const float* h    = (const float*)d_in[0];
  const int*   esrc = (const int*)d_in[1];
  const int*   edst = (const int*)d_in[2];
  const float* W    = (const float*)d_in[3];
  const float* b    = (const float*)d_in[4];
  float* out = (float*)d_out;

  int n_nodes = in_sizes[0] / DIMS;
  int n_edges = in_sizes[1];

  size_t plane = (size_t)n_nodes * NCLS * sizeof(unsigned short);
  size_t need = 2 * ((plane + 255) & ~(size_t)255);
  if (ws_size >= need) {
    unsigned short* Psrc = (unsigned short*)d_ws;
    unsigned short* Pdst = (unsigned short*)((char*)d_ws + ((plane + 255) & ~(size_t)255));
    int blocks1 = (n_nodes + 63) / 64;  // 64 nodes per 256-thread block (4 waves x 16)
    proj_mfma_kernel<<<blocks1, 256, 0, stream>>>(h, W, b, Psrc, Pdst, n_nodes);
    long total = (long)n_edges * 2;     // 2 threads per edge
    int blocks2 = (int)((total + 255) / 256);
    gather2_kernel<<<blocks2, 256, 0, stream>>>(esrc, edst, Psrc, Pdst, out, n_edges);
  } else {
    long total = (long)n_edges * NCLS;
    int blocks2 = (int)((total + 255) / 256);
    direct_kernel<<<blocks2, 256, 0, stream>>>(h, esrc, edst, W, b, out, n_edges);
  }
}